// Round 1
// baseline (1017.391 us; speedup 1.0000x reference)
//
#include <hip/hip_runtime.h>

#define T_DIM 2048
#define D_DIM 64
#define BH 48

typedef _Float16 f16x8 __attribute__((ext_vector_type(8)));
typedef _Float16 f16x4 __attribute__((ext_vector_type(4)));
typedef float f32x4 __attribute__((ext_vector_type(4)));

// fp32 -> fp16 conversion (vectorized), fills workspace
__global__ void cvt_f32_f16(const float* __restrict__ src, _Float16* __restrict__ dst, int n4) {
    int i = blockIdx.x * blockDim.x + threadIdx.x;
    if (i >= n4) return;
    float4 v = ((const float4* __restrict__)src)[i];
    f16x4 h = { (_Float16)v.x, (_Float16)v.y, (_Float16)v.z, (_Float16)v.w };
    ((f16x4*)dst)[i] = h;
}

// One wave owns 32 q-rows (two 16-row m-tiles) of one (b,h).
// SWAPPED MFMA: compute D = K_tile * Q_rows  (A=K, B=Q), so the C/D layout
// (col=lane&15, row=(lane>>4)*4+reg) puts q-row in the lane index (li) and
// FOUR CONSECUTIVE K-COLUMNS in the 4 accumulator regs. Phase-2 writes are
// then one global_store_dwordx4 per m-tile per k-tile (16B/lane, coalesced),
// instead of 16 scalar dword stores.
// Causal masking only happens on the two diagonal tiles (kt=kb for mt0,
// kt=kb+1 for mt1); all bulk tiles are unconditionally unmasked, and the
// fully-masked mt0 sub-tile at kt=kb+1 is a direct zero store.
__global__ __launch_bounds__(256) void sdp_kernel(const _Float16* __restrict__ q16,
                                                  const _Float16* __restrict__ k16,
                                                  float* __restrict__ out) {
    const int T = T_DIM;
    const float scale = 0.125f;  // 64^-0.5

    int bh   = blockIdx.x >> 4;   // 16 blocks per head
    int qblk = blockIdx.x & 15;
    int wave = threadIdx.x >> 6;
    int lane = threadIdx.x & 63;
    int g    = lane >> 4;         // quad (0..3): K-slice selector / k-col group
    int li   = lane & 15;         // q-row within m-tile (C "col"), K-row for A loads
    int qbase = qblk * 128 + wave * 32;

    const _Float16* qh = q16 + (size_t)bh * T * D_DIM;
    const _Float16* kh = k16 + (size_t)bh * T * D_DIM;
    float* oh = out + (size_t)bh * T * T;

    // B (N-side) fragments: the wave's 32 q-rows, hoisted for both phases.
    // B[n=li][k=g*8+j], two K=32 slices.
    f16x8 b_lo[2], b_hi[2];
#pragma unroll
    for (int mt = 0; mt < 2; ++mt) {
        const _Float16* p = qh + (size_t)(qbase + mt * 16 + li) * D_DIM;
        b_lo[mt] = *(const f16x8*)(p + g * 8);
        b_hi[mt] = *(const f16x8*)(p + 32 + g * 8);
    }

    const int kb = qbase >> 4;  // diagonal k-tile index for mt=0 (mt=1 diag is kb+1)

    // ---- Phase 1: row sums of exp (no max pass: |s| <= ~15, exp can't overflow) ----
    float sum0 = 0.f, sum1 = 0.f;
    for (int kt = 0; kt < kb; ++kt) {  // strictly-below-diagonal tiles: no masking
        const _Float16* p = kh + (size_t)(kt * 16 + li) * D_DIM;
        f16x8 a_lo = *(const f16x8*)(p + g * 8);
        f16x8 a_hi = *(const f16x8*)(p + 32 + g * 8);
        f32x4 acc0 = {0.f, 0.f, 0.f, 0.f}, acc1 = {0.f, 0.f, 0.f, 0.f};
        acc0 = __builtin_amdgcn_mfma_f32_16x16x32_f16(a_lo, b_lo[0], acc0, 0, 0, 0);
        acc0 = __builtin_amdgcn_mfma_f32_16x16x32_f16(a_hi, b_hi[0], acc0, 0, 0, 0);
        acc1 = __builtin_amdgcn_mfma_f32_16x16x32_f16(a_lo, b_lo[1], acc1, 0, 0, 0);
        acc1 = __builtin_amdgcn_mfma_f32_16x16x32_f16(a_hi, b_hi[1], acc1, 0, 0, 0);
#pragma unroll
        for (int e = 0; e < 4; ++e) {
            sum0 += __expf(acc0[e] * scale);
            sum1 += __expf(acc1[e] * scale);
        }
    }
    {   // kt = kb: mt0 diagonal (mask g*4+e <= li), mt1 fully unmasked
        const _Float16* p = kh + (size_t)(kb * 16 + li) * D_DIM;
        f16x8 a_lo = *(const f16x8*)(p + g * 8);
        f16x8 a_hi = *(const f16x8*)(p + 32 + g * 8);
        f32x4 acc0 = {0.f, 0.f, 0.f, 0.f}, acc1 = {0.f, 0.f, 0.f, 0.f};
        acc0 = __builtin_amdgcn_mfma_f32_16x16x32_f16(a_lo, b_lo[0], acc0, 0, 0, 0);
        acc0 = __builtin_amdgcn_mfma_f32_16x16x32_f16(a_hi, b_hi[0], acc0, 0, 0, 0);
        acc1 = __builtin_amdgcn_mfma_f32_16x16x32_f16(a_lo, b_lo[1], acc1, 0, 0, 0);
        acc1 = __builtin_amdgcn_mfma_f32_16x16x32_f16(a_hi, b_hi[1], acc1, 0, 0, 0);
        int d = li - g * 4;
#pragma unroll
        for (int e = 0; e < 4; ++e) {
            sum0 += (e <= d) ? __expf(acc0[e] * scale) : 0.f;
            sum1 += __expf(acc1[e] * scale);
        }
    }
    {   // kt = kb+1: only mt1, diagonal-masked
        const _Float16* p = kh + (size_t)((kb + 1) * 16 + li) * D_DIM;
        f16x8 a_lo = *(const f16x8*)(p + g * 8);
        f16x8 a_hi = *(const f16x8*)(p + 32 + g * 8);
        f32x4 acc1 = {0.f, 0.f, 0.f, 0.f};
        acc1 = __builtin_amdgcn_mfma_f32_16x16x32_f16(a_lo, b_lo[1], acc1, 0, 0, 0);
        acc1 = __builtin_amdgcn_mfma_f32_16x16x32_f16(a_hi, b_hi[1], acc1, 0, 0, 0);
        int d = li - g * 4;
#pragma unroll
        for (int e = 0; e < 4; ++e)
            sum1 += (e <= d) ? __expf(acc1[e] * scale) : 0.f;
    }
    // reduce across the 4 g-groups holding the same q-row (lanes li, li+16, li+32, li+48)
    sum0 += __shfl_xor(sum0, 16); sum0 += __shfl_xor(sum0, 32);
    sum1 += __shfl_xor(sum1, 16); sum1 += __shfl_xor(sum1, 32);
    float rinv0 = 1.0f / sum0;
    float rinv1 = 1.0f / sum1;

    // ---- Phase 2: recompute + write normalized probs (dwordx4 stores) ----
    float* rp0 = oh + (size_t)(qbase + li) * T + g * 4;        // mt=0 row ptr
    float* rp1 = rp0 + (size_t)16 * T;                         // mt=1 row ptr
    for (int kt = 0; kt < kb; ++kt) {
        const _Float16* p = kh + (size_t)(kt * 16 + li) * D_DIM;
        f16x8 a_lo = *(const f16x8*)(p + g * 8);
        f16x8 a_hi = *(const f16x8*)(p + 32 + g * 8);
        f32x4 acc0 = {0.f, 0.f, 0.f, 0.f}, acc1 = {0.f, 0.f, 0.f, 0.f};
        acc0 = __builtin_amdgcn_mfma_f32_16x16x32_f16(a_lo, b_lo[0], acc0, 0, 0, 0);
        acc0 = __builtin_amdgcn_mfma_f32_16x16x32_f16(a_hi, b_hi[0], acc0, 0, 0, 0);
        acc1 = __builtin_amdgcn_mfma_f32_16x16x32_f16(a_lo, b_lo[1], acc1, 0, 0, 0);
        acc1 = __builtin_amdgcn_mfma_f32_16x16x32_f16(a_hi, b_hi[1], acc1, 0, 0, 0);
        f32x4 pv0, pv1;
#pragma unroll
        for (int e = 0; e < 4; ++e) {
            pv0[e] = __expf(acc0[e] * scale) * rinv0;
            pv1[e] = __expf(acc1[e] * scale) * rinv1;
        }
        *(f32x4*)(rp0 + kt * 16) = pv0;
        *(f32x4*)(rp1 + kt * 16) = pv1;
    }
    {   // kt = kb: mt0 diagonal-masked, mt1 full
        const _Float16* p = kh + (size_t)(kb * 16 + li) * D_DIM;
        f16x8 a_lo = *(const f16x8*)(p + g * 8);
        f16x8 a_hi = *(const f16x8*)(p + 32 + g * 8);
        f32x4 acc0 = {0.f, 0.f, 0.f, 0.f}, acc1 = {0.f, 0.f, 0.f, 0.f};
        acc0 = __builtin_amdgcn_mfma_f32_16x16x32_f16(a_lo, b_lo[0], acc0, 0, 0, 0);
        acc0 = __builtin_amdgcn_mfma_f32_16x16x32_f16(a_hi, b_hi[0], acc0, 0, 0, 0);
        acc1 = __builtin_amdgcn_mfma_f32_16x16x32_f16(a_lo, b_lo[1], acc1, 0, 0, 0);
        acc1 = __builtin_amdgcn_mfma_f32_16x16x32_f16(a_hi, b_hi[1], acc1, 0, 0, 0);
        int d = li - g * 4;
        f32x4 pv0, pv1;
#pragma unroll
        for (int e = 0; e < 4; ++e) {
            pv0[e] = (e <= d) ? __expf(acc0[e] * scale) * rinv0 : 0.f;
            pv1[e] = __expf(acc1[e] * scale) * rinv1;
        }
        *(f32x4*)(rp0 + kb * 16) = pv0;
        *(f32x4*)(rp1 + kb * 16) = pv1;
    }
    {   // kt = kb+1: mt0 fully masked -> zero store; mt1 diagonal-masked
        const _Float16* p = kh + (size_t)((kb + 1) * 16 + li) * D_DIM;
        f16x8 a_lo = *(const f16x8*)(p + g * 8);
        f16x8 a_hi = *(const f16x8*)(p + 32 + g * 8);
        f32x4 acc1 = {0.f, 0.f, 0.f, 0.f};
        acc1 = __builtin_amdgcn_mfma_f32_16x16x32_f16(a_lo, b_lo[1], acc1, 0, 0, 0);
        acc1 = __builtin_amdgcn_mfma_f32_16x16x32_f16(a_hi, b_hi[1], acc1, 0, 0, 0);
        int d = li - g * 4;
        f32x4 pv1, z4 = {0.f, 0.f, 0.f, 0.f};
#pragma unroll
        for (int e = 0; e < 4; ++e)
            pv1[e] = (e <= d) ? __expf(acc1[e] * scale) * rinv1 : 0.f;
        *(f32x4*)(rp0 + (kb + 1) * 16) = z4;
        *(f32x4*)(rp1 + (kb + 1) * 16) = pv1;
    }

    // ---- Zero tail: cols [qbase+32, T) for this wave's 32 rows ----
    int zstart = qbase + 32;
    float4 z = make_float4(0.f, 0.f, 0.f, 0.f);
    for (int rr = 0; rr < 32; ++rr) {
        float* rowp = oh + (size_t)(qbase + rr) * T;
        for (int cc = zstart + lane * 4; cc < T; cc += 256)
            *(float4*)(rowp + cc) = z;
    }
}

extern "C" void kernel_launch(void* const* d_in, const int* in_sizes, int n_in,
                              void* d_out, int out_size, void* d_ws, size_t ws_size,
                              hipStream_t stream) {
    const float* q = (const float*)d_in[0];
    const float* k = (const float*)d_in[1];
    float* out = (float*)d_out;

    _Float16* q16 = (_Float16*)d_ws;
    _Float16* k16 = q16 + (size_t)BH * T_DIM * D_DIM;

    int n  = BH * T_DIM * D_DIM;   // 6,291,456 per tensor
    int n4 = n / 4;
    cvt_f32_f16<<<(n4 + 255) / 256, 256, 0, stream>>>(q, q16, n4);
    cvt_f32_f16<<<(n4 + 255) / 256, 256, 0, stream>>>(k, k16, n4);

    sdp_kernel<<<BH * 16, 256, 0, stream>>>(q16, k16, out);
}

// Round 2
// 1015.780 us; speedup vs baseline: 1.0016x; 1.0016x over previous
//
#include <hip/hip_runtime.h>

#define T_DIM 2048
#define D_DIM 64
#define BH 48

typedef _Float16 f16x8 __attribute__((ext_vector_type(8)));
typedef _Float16 f16x4 __attribute__((ext_vector_type(4)));
typedef float f32x4 __attribute__((ext_vector_type(4)));

// fp32 -> fp16 conversion (vectorized), fills workspace
__global__ void cvt_f32_f16(const float* __restrict__ src, _Float16* __restrict__ dst, int n4) {
    int i = blockIdx.x * blockDim.x + threadIdx.x;
    if (i >= n4) return;
    float4 v = ((const float4* __restrict__)src)[i];
    f16x4 h = { (_Float16)v.x, (_Float16)v.y, (_Float16)v.z, (_Float16)v.w };
    ((f16x4*)dst)[i] = h;
}

// One wave owns 32 q-rows (two 16-row m-tiles) of one (b,h).
// SWAPPED MFMA: D = K_tile * Q_rows (A=K, B=Q) so lane holds q-row (li) and 4
// consecutive k-columns in the 4 acc regs -> one dwordx4 store per m-tile/k-tile.
//
// XCD-LOCALITY MAP (round 2): blocks are decoded so that all 16 q-chunks of a
// head land on the SAME XCD (wg i -> XCD i%8 on MI355X). Per-XCD working set
// becomes 6 heads * (K+Q = 512 KB) = 3 MB < 4 MB L2, making every K-fragment
// load an L2 hit instead of an Infinity-Cache bounce. Heavy/light q-chunks are
// interleaved in dispatch order to balance causal work across CUs.
__global__ __launch_bounds__(256) void sdp_kernel(const _Float16* __restrict__ q16,
                                                  const _Float16* __restrict__ k16,
                                                  float* __restrict__ out) {
    const int T = T_DIM;
    const float scale = 0.125f;  // 64^-0.5

    // ---- block decode: head-per-XCD + work-balanced q-chunk order ----
    int b    = blockIdx.x;       // 0..767
    int xcd  = b & 7;
    int t    = b >> 3;           // 0..95
    int qraw = t & 15;           // dispatch-order slot within head
    int grp  = t >> 4;           // 0..5
    int bh   = xcd + 8 * grp;    // head 0..47, pinned to XCD = bh%8
    int qm   = qraw >> 1;
    int qblk = (qraw & 1) ? (15 - qm) : qm;   // 0,15,1,14,... light/heavy mix

    int wave = threadIdx.x >> 6;
    int lane = threadIdx.x & 63;
    int g    = lane >> 4;         // quad (0..3): K-slice selector / k-col group
    int li   = lane & 15;         // q-row within m-tile (C "col"), K-row for A loads
    int qbase = qblk * 128 + wave * 32;

    const _Float16* qh = q16 + (size_t)bh * T * D_DIM;
    const _Float16* kh = k16 + (size_t)bh * T * D_DIM;
    float* oh = out + (size_t)bh * T * T;

    // B (N-side) fragments: the wave's 32 q-rows, hoisted for both phases.
    f16x8 b_lo[2], b_hi[2];
#pragma unroll
    for (int mt = 0; mt < 2; ++mt) {
        const _Float16* p = qh + (size_t)(qbase + mt * 16 + li) * D_DIM;
        b_lo[mt] = *(const f16x8*)(p + g * 8);
        b_hi[mt] = *(const f16x8*)(p + 32 + g * 8);
    }

    const int kb = qbase >> 4;  // diagonal k-tile index for mt=0 (mt=1 diag is kb+1)

    // ---- Phase 1: row sums of exp (no max pass: |s| <= ~15, exp can't overflow) ----
    float sum0 = 0.f, sum1 = 0.f;
#pragma unroll 2
    for (int kt = 0; kt < kb; ++kt) {  // strictly-below-diagonal tiles: no masking
        const _Float16* p = kh + (size_t)(kt * 16 + li) * D_DIM;
        f16x8 a_lo = *(const f16x8*)(p + g * 8);
        f16x8 a_hi = *(const f16x8*)(p + 32 + g * 8);
        f32x4 acc0 = {0.f, 0.f, 0.f, 0.f}, acc1 = {0.f, 0.f, 0.f, 0.f};
        acc0 = __builtin_amdgcn_mfma_f32_16x16x32_f16(a_lo, b_lo[0], acc0, 0, 0, 0);
        acc0 = __builtin_amdgcn_mfma_f32_16x16x32_f16(a_hi, b_hi[0], acc0, 0, 0, 0);
        acc1 = __builtin_amdgcn_mfma_f32_16x16x32_f16(a_lo, b_lo[1], acc1, 0, 0, 0);
        acc1 = __builtin_amdgcn_mfma_f32_16x16x32_f16(a_hi, b_hi[1], acc1, 0, 0, 0);
#pragma unroll
        for (int e = 0; e < 4; ++e) {
            sum0 += __expf(acc0[e] * scale);
            sum1 += __expf(acc1[e] * scale);
        }
    }
    {   // kt = kb: mt0 diagonal (mask g*4+e <= li), mt1 fully unmasked
        const _Float16* p = kh + (size_t)(kb * 16 + li) * D_DIM;
        f16x8 a_lo = *(const f16x8*)(p + g * 8);
        f16x8 a_hi = *(const f16x8*)(p + 32 + g * 8);
        f32x4 acc0 = {0.f, 0.f, 0.f, 0.f}, acc1 = {0.f, 0.f, 0.f, 0.f};
        acc0 = __builtin_amdgcn_mfma_f32_16x16x32_f16(a_lo, b_lo[0], acc0, 0, 0, 0);
        acc0 = __builtin_amdgcn_mfma_f32_16x16x32_f16(a_hi, b_hi[0], acc0, 0, 0, 0);
        acc1 = __builtin_amdgcn_mfma_f32_16x16x32_f16(a_lo, b_lo[1], acc1, 0, 0, 0);
        acc1 = __builtin_amdgcn_mfma_f32_16x16x32_f16(a_hi, b_hi[1], acc1, 0, 0, 0);
        int d = li - g * 4;
#pragma unroll
        for (int e = 0; e < 4; ++e) {
            sum0 += (e <= d) ? __expf(acc0[e] * scale) : 0.f;
            sum1 += __expf(acc1[e] * scale);
        }
    }
    {   // kt = kb+1: only mt1, diagonal-masked
        const _Float16* p = kh + (size_t)((kb + 1) * 16 + li) * D_DIM;
        f16x8 a_lo = *(const f16x8*)(p + g * 8);
        f16x8 a_hi = *(const f16x8*)(p + 32 + g * 8);
        f32x4 acc1 = {0.f, 0.f, 0.f, 0.f};
        acc1 = __builtin_amdgcn_mfma_f32_16x16x32_f16(a_lo, b_lo[1], acc1, 0, 0, 0);
        acc1 = __builtin_amdgcn_mfma_f32_16x16x32_f16(a_hi, b_hi[1], acc1, 0, 0, 0);
        int d = li - g * 4;
#pragma unroll
        for (int e = 0; e < 4; ++e)
            sum1 += (e <= d) ? __expf(acc1[e] * scale) : 0.f;
    }
    // reduce across the 4 g-groups holding the same q-row (lanes li, li+16, li+32, li+48)
    sum0 += __shfl_xor(sum0, 16); sum0 += __shfl_xor(sum0, 32);
    sum1 += __shfl_xor(sum1, 16); sum1 += __shfl_xor(sum1, 32);
    float rinv0 = 1.0f / sum0;
    float rinv1 = 1.0f / sum1;

    // ---- Phase 2: recompute + write normalized probs (dwordx4 stores) ----
    float* rp0 = oh + (size_t)(qbase + li) * T + g * 4;        // mt=0 row ptr
    float* rp1 = rp0 + (size_t)16 * T;                         // mt=1 row ptr
#pragma unroll 2
    for (int kt = 0; kt < kb; ++kt) {
        const _Float16* p = kh + (size_t)(kt * 16 + li) * D_DIM;
        f16x8 a_lo = *(const f16x8*)(p + g * 8);
        f16x8 a_hi = *(const f16x8*)(p + 32 + g * 8);
        f32x4 acc0 = {0.f, 0.f, 0.f, 0.f}, acc1 = {0.f, 0.f, 0.f, 0.f};
        acc0 = __builtin_amdgcn_mfma_f32_16x16x32_f16(a_lo, b_lo[0], acc0, 0, 0, 0);
        acc0 = __builtin_amdgcn_mfma_f32_16x16x32_f16(a_hi, b_hi[0], acc0, 0, 0, 0);
        acc1 = __builtin_amdgcn_mfma_f32_16x16x32_f16(a_lo, b_lo[1], acc1, 0, 0, 0);
        acc1 = __builtin_amdgcn_mfma_f32_16x16x32_f16(a_hi, b_hi[1], acc1, 0, 0, 0);
        f32x4 pv0, pv1;
#pragma unroll
        for (int e = 0; e < 4; ++e) {
            pv0[e] = __expf(acc0[e] * scale) * rinv0;
            pv1[e] = __expf(acc1[e] * scale) * rinv1;
        }
        *(f32x4*)(rp0 + kt * 16) = pv0;
        *(f32x4*)(rp1 + kt * 16) = pv1;
    }
    {   // kt = kb: mt0 diagonal-masked, mt1 full
        const _Float16* p = kh + (size_t)(kb * 16 + li) * D_DIM;
        f16x8 a_lo = *(const f16x8*)(p + g * 8);
        f16x8 a_hi = *(const f16x8*)(p + 32 + g * 8);
        f32x4 acc0 = {0.f, 0.f, 0.f, 0.f}, acc1 = {0.f, 0.f, 0.f, 0.f};
        acc0 = __builtin_amdgcn_mfma_f32_16x16x32_f16(a_lo, b_lo[0], acc0, 0, 0, 0);
        acc0 = __builtin_amdgcn_mfma_f32_16x16x32_f16(a_hi, b_hi[0], acc0, 0, 0, 0);
        acc1 = __builtin_amdgcn_mfma_f32_16x16x32_f16(a_lo, b_lo[1], acc1, 0, 0, 0);
        acc1 = __builtin_amdgcn_mfma_f32_16x16x32_f16(a_hi, b_hi[1], acc1, 0, 0, 0);
        int d = li - g * 4;
        f32x4 pv0, pv1;
#pragma unroll
        for (int e = 0; e < 4; ++e) {
            pv0[e] = (e <= d) ? __expf(acc0[e] * scale) * rinv0 : 0.f;
            pv1[e] = __expf(acc1[e] * scale) * rinv1;
        }
        *(f32x4*)(rp0 + kb * 16) = pv0;
        *(f32x4*)(rp1 + kb * 16) = pv1;
    }
    {   // kt = kb+1: mt0 fully masked -> zero store; mt1 diagonal-masked
        const _Float16* p = kh + (size_t)((kb + 1) * 16 + li) * D_DIM;
        f16x8 a_lo = *(const f16x8*)(p + g * 8);
        f16x8 a_hi = *(const f16x8*)(p + 32 + g * 8);
        f32x4 acc1 = {0.f, 0.f, 0.f, 0.f};
        acc1 = __builtin_amdgcn_mfma_f32_16x16x32_f16(a_lo, b_lo[1], acc1, 0, 0, 0);
        acc1 = __builtin_amdgcn_mfma_f32_16x16x32_f16(a_hi, b_hi[1], acc1, 0, 0, 0);
        int d = li - g * 4;
        f32x4 pv1, z4 = {0.f, 0.f, 0.f, 0.f};
#pragma unroll
        for (int e = 0; e < 4; ++e)
            pv1[e] = (e <= d) ? __expf(acc1[e] * scale) * rinv1 : 0.f;
        *(f32x4*)(rp0 + (kb + 1) * 16) = z4;
        *(f32x4*)(rp1 + (kb + 1) * 16) = pv1;
    }

    // ---- Zero tail: cols [qbase+32, T) for this wave's 32 rows ----
    int zstart = qbase + 32;
    float4 z = make_float4(0.f, 0.f, 0.f, 0.f);
    for (int rr = 0; rr < 32; ++rr) {
        float* rowp = oh + (size_t)(qbase + rr) * T;
        for (int cc = zstart + lane * 4; cc < T; cc += 256)
            *(float4*)(rowp + cc) = z;
    }
}

extern "C" void kernel_launch(void* const* d_in, const int* in_sizes, int n_in,
                              void* d_out, int out_size, void* d_ws, size_t ws_size,
                              hipStream_t stream) {
    const float* q = (const float*)d_in[0];
    const float* k = (const float*)d_in[1];
    float* out = (float*)d_out;

    _Float16* q16 = (_Float16*)d_ws;
    _Float16* k16 = q16 + (size_t)BH * T_DIM * D_DIM;

    int n  = BH * T_DIM * D_DIM;   // 6,291,456 per tensor
    int n4 = n / 4;
    cvt_f32_f16<<<(n4 + 255) / 256, 256, 0, stream>>>(q, q16, n4);
    cvt_f32_f16<<<(n4 + 255) / 256, 256, 0, stream>>>(k, k16, n4);

    sdp_kernel<<<BH * 16, 256, 0, stream>>>(q16, k16, out);
}